// Round 3
// baseline (17803.966 us; speedup 1.0000x reference)
//
#include <hip/hip_runtime.h>
#include <hip/hip_fp16.h>
#include <math.h>

// ---------------------------------------------------------------------------
// ODERGRU pipeline for MI355X.
//  K1: einsum -> h1 (3200,96,29)
//  K2: conv1d 96->96 k5 + bias -> h2 + BN partials
//  K3: BN1 reduce (parallel, f64 tree)
//  K4: conv1d 96->16 k5 (BN1+lrelu on load) -> h3 + BN2 partials
//  K5: BN2 reduce
//  K6: OAS + Cholesky -> x_d, x_o
//  K0: pack ODE/GRU weights f32 -> f16x2 (into dead h2 region)
//  K7: per-batch-row scan; 512 thr; pair-lane K-split; w0/w1/w2 cols in VGPR
//      (162 u32/thread), w3 in LDS; combine via __shfl_xor(.,1) (same wave)
// ---------------------------------------------------------------------------

#define BB 64
#define NIMG 3200

__device__ __forceinline__ float sigm(float x) { return 1.f / (1.f + expf(-x)); }

// ------------------------------ K1: filterbank ------------------------------
__global__ __launch_bounds__(256) void k1_fb(const float* __restrict__ x,
                                             const float* __restrict__ fw,
                                             const float* __restrict__ st,
                                             float* __restrict__ h1) {
  __shared__ __align__(16) float ws[129 * 32];
  __shared__ __align__(16) float xs[129 * 32];
  const int tid = threadIdx.x;
  const int n = blockIdx.x;
  const float* xp = x + (size_t)n * 11223;

  for (int i = tid; i < 4128; i += 256) ws[i] = fw[i] * st[i];

  float acc[4][4];
#pragma unroll
  for (int i = 0; i < 4; ++i)
#pragma unroll
    for (int j = 0; j < 4; ++j) acc[i][j] = 0.f;

  const int c = tid / 64;
  const int rem = tid % 64;
  const int m0 = (rem / 8) * 4;
  const int t0 = (rem % 8) * 4;

  for (int fc = 0; fc < 3; ++fc) {
    __syncthreads();
    for (int i = tid; i < 3741; i += 256) {
      int cc = i / 1247;
      int r = i - cc * 1247;
      int f = r / 29;
      int t = r - f * 29;
      xs[(cc * 43 + f) * 32 + t] = xp[cc * 3741 + (fc * 43 + f) * 29 + t];
    }
    for (int i = tid; i < 129; i += 256) {
      xs[i * 32 + 29] = 0.f; xs[i * 32 + 30] = 0.f; xs[i * 32 + 31] = 0.f;
    }
    __syncthreads();
    if (tid < 192) {
      const float* xb = xs + (c * 43) * 32 + t0;
      const float* wb = ws + (fc * 43) * 32 + m0;
      for (int f = 0; f < 43; ++f) {
        float4 xv = *(const float4*)(xb + f * 32);
        float4 wv = *(const float4*)(wb + f * 32);
        float xa[4] = {xv.x, xv.y, xv.z, xv.w};
        float wa[4] = {wv.x, wv.y, wv.z, wv.w};
#pragma unroll
        for (int i = 0; i < 4; ++i)
#pragma unroll
          for (int j = 0; j < 4; ++j) acc[i][j] += wa[i] * xa[j];
      }
    }
  }
  if (tid < 192) {
    const int nt = (t0 == 28) ? 1 : 4;
    for (int i = 0; i < 4; ++i)
      for (int j = 0; j < nt; ++j)
        h1[(size_t)n * 2784 + (size_t)(c * 32 + m0 + i) * 29 + (t0 + j)] = acc[i][j];
  }
}

// ------------------------------ K2: conv1 ------------------------------
__global__ __launch_bounds__(256) void k2_conv1(const float* __restrict__ h1,
                                                const float* __restrict__ w,
                                                const float* __restrict__ bias,
                                                float* __restrict__ h2,
                                                float* __restrict__ part1) {
  __shared__ __align__(16) float ins[2 * 96 * 32];
  __shared__ __align__(16) float wls[96 * 81];
  const int tid = threadIdx.x;
  const int wg = blockIdx.x;

  for (int i = tid; i < 2 * 2784; i += 256) {
    int img = i / 2784;
    int e = i - img * 2784;
    int ci = e / 29;
    int t = e - ci * 29;
    ins[img * 3072 + ci * 32 + t] = h1[(size_t)(wg * 2 + img) * 2784 + e];
  }

  const int img = tid / 96;
  const int co = tid - img * 96;
  float acc[25];
#pragma unroll
  for (int t = 0; t < 25; ++t) acc[t] = 0.f;

  for (int cc = 0; cc < 6; ++cc) {
    __syncthreads();
    for (int i = tid; i < 7680; i += 256) {
      int cw = i / 80;
      int r = i - cw * 80;
      wls[cw * 81 + r] = w[cw * 480 + cc * 80 + r];
    }
    __syncthreads();
    if (tid < 192) {
      for (int ci = 0; ci < 16; ++ci) {
        float xv[29];
#pragma unroll
        for (int j = 0; j < 29; ++j) xv[j] = ins[img * 3072 + (cc * 16 + ci) * 32 + j];
        float wv[5];
#pragma unroll
        for (int d = 0; d < 5; ++d) wv[d] = wls[co * 81 + ci * 5 + d];
#pragma unroll
        for (int t = 0; t < 25; ++t) {
          float s = acc[t];
#pragma unroll
          for (int d = 0; d < 5; ++d) s += xv[t + d] * wv[d];
          acc[t] = s;
        }
      }
    }
  }
  if (tid < 192) {
    const int n = wg * 2 + img;
    const float bval = bias[co];
    float s1 = 0.f, s2 = 0.f;
    for (int t = 0; t < 25; ++t) {
      float v = acc[t] + bval;
      h2[(size_t)n * 2400 + co * 25 + t] = v;
      s1 += v;
      s2 += v * v;
    }
    part1[((size_t)n * 96 + co) * 2 + 0] = s1;
    part1[((size_t)n * 96 + co) * 2 + 1] = s2;
  }
}

// ------------------------------ K3/K5: BN reduce (parallel) -----------------
__global__ __launch_bounds__(256) void k3_bn1(const float* __restrict__ part,
                                              const float* __restrict__ gg,
                                              const float* __restrict__ be,
                                              float* __restrict__ ab) {
  __shared__ double sd[256], sq[256];
  const int c = blockIdx.x;       // 96
  const int t = threadIdx.x;
  double s = 0.0, q = 0.0;
  for (int n = t; n < NIMG; n += 256) {
    s += (double)part[((size_t)n * 96 + c) * 2 + 0];
    q += (double)part[((size_t)n * 96 + c) * 2 + 1];
  }
  sd[t] = s; sq[t] = q;
  __syncthreads();
  for (int off = 128; off > 0; off >>= 1) {
    if (t < off) { sd[t] += sd[t + off]; sq[t] += sq[t + off]; }
    __syncthreads();
  }
  if (t == 0) {
    double mu = sd[0] / 80000.0;
    double var = sq[0] / 80000.0 - mu * mu;
    float A = (float)((double)gg[c] / sqrt(var + 1e-5));
    ab[c * 2 + 0] = A;
    ab[c * 2 + 1] = (float)((double)be[c] - mu * (double)A);
  }
}

__global__ __launch_bounds__(256) void k5_bn2(const float* __restrict__ part,
                                              const float* __restrict__ gg,
                                              const float* __restrict__ be,
                                              float* __restrict__ ab) {
  __shared__ double sd[256], sq[256];
  const int c = blockIdx.x;       // 16
  const int t = threadIdx.x;
  double s = 0.0, q = 0.0;
  for (int n = t; n < 800; n += 256) {
    s += (double)part[((size_t)n * 16 + c) * 2 + 0];
    q += (double)part[((size_t)n * 16 + c) * 2 + 1];
  }
  sd[t] = s; sq[t] = q;
  __syncthreads();
  for (int off = 128; off > 0; off >>= 1) {
    if (t < off) { sd[t] += sd[t + off]; sq[t] += sq[t + off]; }
    __syncthreads();
  }
  if (t == 0) {
    double mu = sd[0] / 67200.0;
    double var = sq[0] / 67200.0 - mu * mu;
    float A = (float)((double)gg[c] / sqrt(var + 1e-5));
    ab[c * 2 + 0] = A;
    ab[c * 2 + 1] = (float)((double)be[c] - mu * (double)A);
  }
}

// ------------------------------ K4: conv2 ------------------------------
__global__ __launch_bounds__(256) void k4_conv2(const float* __restrict__ h2,
                                                const float* __restrict__ w,
                                                const float* __restrict__ bias,
                                                const float* __restrict__ bn1,
                                                float* __restrict__ h3,
                                                float* __restrict__ part2) {
  __shared__ __align__(16) float ins[4 * 96 * 26];
  __shared__ __align__(16) float wls[16 * 241];
  __shared__ float A1s[96], B1s[96];
  __shared__ float red[16 * 16 * 2];
  const int tid = threadIdx.x;
  const int wg = blockIdx.x;

  if (tid < 96) {
    A1s[tid] = bn1[tid * 2 + 0];
    B1s[tid] = bn1[tid * 2 + 1];
  }
  __syncthreads();
  for (int i = tid; i < 9600; i += 256) {
    int img = i / 2400;
    int e = i - img * 2400;
    int ci = e / 25;
    int t = e - ci * 25;
    float v = h2[(size_t)(wg * 4 + img) * 2400 + e];
    v = A1s[ci] * v + B1s[ci];
    v = (v >= 0.f) ? v : 0.01f * v;
    ins[img * 2496 + ci * 26 + t] = v;
  }
  for (int i = tid; i < 4 * 96; i += 256) ins[(i / 96) * 2496 + (i % 96) * 26 + 25] = 0.f;

  const int img = tid >> 6;
  const int co = (tid >> 2) & 15;
  const int tg = tid & 3;
  const int t0s[4] = {0, 6, 11, 16};
  const int t0 = t0s[tg];
  const int tl = (tg == 0) ? 6 : 5;
  float acc[6] = {0.f, 0.f, 0.f, 0.f, 0.f, 0.f};

  for (int cc = 0; cc < 2; ++cc) {
    __syncthreads();
    for (int i = tid; i < 3840; i += 256) {
      int cw = i / 240;
      int r = i - cw * 240;
      wls[cw * 241 + r] = w[cw * 480 + cc * 240 + r];
    }
    __syncthreads();
    for (int ci = 0; ci < 48; ++ci) {
      float xv[10];
#pragma unroll
      for (int j = 0; j < 10; ++j) xv[j] = ins[img * 2496 + (cc * 48 + ci) * 26 + t0 + j];
      float wv[5];
#pragma unroll
      for (int d = 0; d < 5; ++d) wv[d] = wls[co * 241 + ci * 5 + d];
#pragma unroll
      for (int t = 0; t < 6; ++t) {
        float s = acc[t];
#pragma unroll
        for (int d = 0; d < 5; ++d) s += xv[t + d] * wv[d];
        acc[t] = s;
      }
    }
  }
  const float bval = bias[co];
  float s1 = 0.f, s2 = 0.f;
  const int n = wg * 4 + img;
  for (int t = 0; t < 6; ++t) {
    if (t < tl) {
      float v = acc[t] + bval;
      h3[(size_t)n * 336 + co * 21 + t0 + t] = v;
      s1 += v;
      s2 += v * v;
    }
  }
  red[(co * 16 + img * 4 + tg) * 2 + 0] = s1;
  red[(co * 16 + img * 4 + tg) * 2 + 1] = s2;
  __syncthreads();
  if (tid < 16) {
    float s = 0.f, q = 0.f;
    for (int k = 0; k < 16; ++k) {
      s += red[(tid * 16 + k) * 2 + 0];
      q += red[(tid * 16 + k) * 2 + 1];
    }
    part2[((size_t)wg * 16 + tid) * 2 + 0] = s;
    part2[((size_t)wg * 16 + tid) * 2 + 1] = q;
  }
}

// ------------------------------ K6: OAS + Cholesky ------------------------------
__global__ __launch_bounds__(256) void k6_oas(const float* __restrict__ h3,
                                              const float* __restrict__ bn2,
                                              float* __restrict__ xd,
                                              float* __restrict__ xo) {
  __shared__ float X[4][21 * 17 + 3];
  __shared__ float A[4][16 * 17];
  __shared__ float mcol[4][16];
  const int tid = threadIdx.x;
  const int wid = tid >> 6;
  const int lane = tid & 63;
  const int n = blockIdx.x * 4 + wid;
  const float* hp = h3 + (size_t)n * 336;

  for (int e = lane; e < 336; e += 64) {
    int c = e / 21;
    int t = e - c * 21;
    float v = hp[e];
    v = bn2[c * 2 + 0] * v + bn2[c * 2 + 1];
    v = (v >= 0.f) ? v : 0.01f * v;
    X[wid][t * 17 + c] = v;
  }
  __syncthreads();
  if (lane < 16) {
    float s = 0.f;
    for (int t = 0; t < 21; ++t) s += X[wid][t * 17 + lane];
    mcol[wid][lane] = s * (1.f / 21.f);
  }
  __syncthreads();
  for (int e = lane; e < 336; e += 64) {
    int t = e / 16;
    int c = e - t * 16;
    X[wid][t * 17 + c] -= mcol[wid][c];
  }
  __syncthreads();

  float tr_p = 0.f, al_p = 0.f;
  float ent[3];
  int ei[3], ej[3], ne = 0;
  for (int e = lane; e < 136; e += 64) {
    int i = 0, e2 = e;
    while (e2 >= 16 - i) { e2 -= 16 - i; i++; }
    int j = i + e2;
    float s = 0.f;
    for (int t = 0; t < 21; ++t) s += X[wid][t * 17 + i] * X[wid][t * 17 + j];
    s *= (1.f / 20.f);
    ent[ne] = s; ei[ne] = i; ej[ne] = j; ne++;
    if (i == j) tr_p += s;
    al_p += s * s * ((i == j) ? 1.f : 2.f);
  }
  for (int m = 1; m < 64; m <<= 1) {
    tr_p += __shfl_xor(tr_p, m);
    al_p += __shfl_xor(al_p, m);
  }
  const float mu = tr_p * (1.f / 16.f);
  const float alpha = al_p * (1.f / 256.f);
  const float num = alpha + mu * mu;
  const float den = 22.f * (alpha - mu * mu * (1.f / 16.f));
  const float shr = (den == 0.f) ? 1.f : fminf(num / den, 1.f);
  for (int q = 0; q < ne; ++q) {
    float c = (1.f - shr) * ent[q] + ((ei[q] == ej[q]) ? shr * mu : 0.f);
    A[wid][ei[q] * 17 + ej[q]] = c;
    A[wid][ej[q] * 17 + ei[q]] = c;
  }
  __syncthreads();

  for (int k = 0; k < 16; ++k) {
    float akk = A[wid][k * 17 + k];
    __syncthreads();
    float d = sqrtf(akk);
    float rd = 1.f / d;
    if (lane == k) A[wid][k * 17 + k] = d;
    if (lane > k && lane < 16) A[wid][lane * 17 + k] *= rd;
    __syncthreads();
    if (lane > k && lane < 16) {
      float Lik = A[wid][lane * 17 + k];
      for (int j = k + 1; j <= lane; ++j) A[wid][lane * 17 + j] -= Lik * A[wid][j * 17 + k];
    }
    __syncthreads();
  }
  if (lane < 16) xd[(size_t)n * 16 + lane] = A[wid][lane * 17 + lane];
  for (int p = lane; p < 120; p += 64) {
    int i = 1, p2 = p;
    while (p2 >= i) { p2 -= i; i++; }
    xo[(size_t)n * 120 + p] = A[wid][i * 17 + p2];
  }
}

// ------------------------------ K0: weight pack (f32 -> f16x2) --------------
#define PK_TOT 143552
__global__ __launch_bounds__(256) void k0_pack(const float* __restrict__ w0,
                                               const float* __restrict__ w1,
                                               const float* __restrict__ w2,
                                               const float* __restrict__ w3,
                                               const float* __restrict__ wxo,
                                               const float* __restrict__ who,
                                               uint32_t* __restrict__ dst) {
  int i = blockIdx.x * 256 + threadIdx.x;
  if (i >= PK_TOT) return;
  float a, bf;
  if (i < 17408) {
    int p = i >> 8, j = i & 255;
    a = w0[(2 * p) * 256 + j]; bf = w0[(2 * p + 1) * 256 + j];
  } else if (i < 50176) {
    int t = i - 17408; int p = t >> 8, j = t & 255;
    a = w1[(2 * p) * 256 + j]; bf = w1[(2 * p + 1) * 256 + j];
  } else if (i < 82944) {
    int t = i - 50176; int p = t >> 8, j = t & 255;
    a = w2[(2 * p) * 256 + j]; bf = w2[(2 * p + 1) * 256 + j];
  } else if (i < 100352) {
    int t = i - 82944; int p = t / 136, c = t - p * 136;
    a = w3[(2 * p) * 136 + c]; bf = w3[(2 * p + 1) * 136 + c];
  } else if (i < 121952) {
    int t = i - 100352; int p = t / 360, c = t - p * 360;
    a = wxo[(2 * p) * 360 + c]; bf = wxo[(2 * p + 1) * 360 + c];
  } else {
    int t = i - 121952; int p = t / 360, c = t - p * 360;
    a = who[(2 * p) * 360 + c]; bf = who[(2 * p + 1) * 360 + c];
  }
  __half2 h = __floats2half2_rn(a, bf);
  dst[i] = *reinterpret_cast<uint32_t*>(&h);
}

// ------------------------------ K7: scan (pair-lane split-K residency) ------
__global__ __launch_bounds__(512, 1) void k7_scan(
    const float* __restrict__ xdv, const float* __restrict__ xov,
    const float* __restrict__ wxd, const float* __restrict__ whd,
    const float* __restrict__ bdv, const float* __restrict__ bov,
    const uint32_t* __restrict__ pk,
    const float* __restrict__ b0, const float* __restrict__ b1,
    const float* __restrict__ b2, const float* __restrict__ b3,
    const float* __restrict__ cw, const float* __restrict__ cbv,
    float* __restrict__ out) {
  __shared__ uint32_t w3s[17408];                    // full packed w3, 69632 B
  __shared__ __align__(16) float hc[136];
  __shared__ __align__(16) float bufA[256];
  __shared__ __align__(16) float bufB[256];
  __shared__ __align__(16) float xdl[16];
  __shared__ __align__(16) float xol[120];
  __shared__ __align__(16) float g[720];
  __shared__ __align__(16) float g2[96];
  const int tid = threadIdx.x;
  const int j = tid >> 1;
  const int h = tid & 1;
  const int b = blockIdx.x;

  const uint32_t* w0p = pk;
  const uint32_t* w1p = pk + 17408;
  const uint32_t* w2p = pk + 50176;
  const uint32_t* w3p = pk + 82944;
  const uint32_t* wxop = pk + 100352;
  const uint32_t* whop = pk + 121952;

  for (int i = tid; i < 17408; i += 512) w3s[i] = w3p[i];

  uint32_t w0r[34], w1r[64], w2r[64];
#pragma unroll
  for (int p = 0; p < 34; ++p) w0r[p] = w0p[(h * 34 + p) * 256 + j];
#pragma unroll
  for (int p = 0; p < 64; ++p) w1r[p] = w1p[(h * 64 + p) * 256 + j];
#pragma unroll
  for (int p = 0; p < 64; ++p) w2r[p] = w2p[(h * 64 + p) * 256 + j];

  const float bj0 = b0[j], bj1 = b1[j], bj2 = b2[j];
  const float bj3 = (j < 136) ? b3[j] : 0.f;

  if (tid < 136) hc[tid] = 0.f;
  __syncthreads();

#pragma unroll 1
  for (int s = 0; s < 50; ++s) {
    if (tid < 16) xdl[tid] = xdv[(size_t)(b * 50 + s) * 16 + tid];
    if (tid >= 16 && tid < 136) xol[tid - 16] = xov[(size_t)(b * 50 + s) * 120 + (tid - 16)];

#pragma unroll 1
    for (int e = 0; e < 4; ++e) {
      // L1: hc(136) -> bufA(256) tanh ; K-half h covers hc[h*68 .. h*68+68)
      {
        float acc = 0.f;
        const float4* h4 = (const float4*)hc;
#pragma unroll
        for (int c = 0; c < 17; ++c) {
          float4 x4 = h4[h * 17 + c];
          float2 wa = __half22float2(*(const __half2*)&w0r[2 * c]);
          float2 wb = __half22float2(*(const __half2*)&w0r[2 * c + 1]);
          acc += x4.x * wa.x + x4.y * wa.y + x4.z * wb.x + x4.w * wb.y;
        }
        float full = acc + __shfl_xor(acc, 1) + bj0;
        if (h == 0) bufA[j] = tanhf(full);
      }
      __syncthreads();
      // L2: bufA -> bufB tanh
      {
        float acc = 0.f;
        const float4* a4 = (const float4*)bufA;
#pragma unroll
        for (int c = 0; c < 32; ++c) {
          float4 x4 = a4[h * 32 + c];
          float2 wa = __half22float2(*(const __half2*)&w1r[2 * c]);
          float2 wb = __half22float2(*(const __half2*)&w1r[2 * c + 1]);
          acc += x4.x * wa.x + x4.y * wa.y + x4.z * wb.x + x4.w * wb.y;
        }
        float full = acc + __shfl_xor(acc, 1) + bj1;
        if (h == 0) bufB[j] = tanhf(full);
      }
      __syncthreads();
      // L3: bufB -> bufA tanh
      {
        float acc = 0.f;
        const float4* a4 = (const float4*)bufB;
#pragma unroll
        for (int c = 0; c < 32; ++c) {
          float4 x4 = a4[h * 32 + c];
          float2 wa = __half22float2(*(const __half2*)&w2r[2 * c]);
          float2 wb = __half22float2(*(const __half2*)&w2r[2 * c + 1]);
          acc += x4.x * wa.x + x4.y * wa.y + x4.z * wb.x + x4.w * wb.y;
        }
        float full = acc + __shfl_xor(acc, 1) + bj2;
        if (h == 0) bufA[j] = tanhf(full);
      }
      __syncthreads();
      // L4: bufA -> hc += 0.25*(w3^T bufA + b3) ; w3 from LDS
      if (j < 136) {
        float acc = 0.f;
        const float4* a4 = (const float4*)bufA;
#pragma unroll
        for (int c = 0; c < 32; ++c) {
          float4 x4 = a4[h * 32 + c];
          int p = h * 64 + 2 * c;
          float2 wa = __half22float2(*(const __half2*)&w3s[p * 136 + j]);
          float2 wb = __half22float2(*(const __half2*)&w3s[(p + 1) * 136 + j]);
          acc += x4.x * wa.x + x4.y * wa.y + x4.z * wb.x + x4.w * wb.y;
        }
        float full = acc + __shfl_xor(acc, 1) + bj3;
        if (h == 0) hc[j] += 0.25f * full;
      }
      __syncthreads();
    }

    // Gates: 720 o-dots (K=120, packed f16) + 96 d-dots (K=16, f32)
    for (int idx = tid; idx < 816; idx += 512) {
      if (idx < 720) {
        const int which = (idx >= 360) ? 1 : 0;
        const int col = which ? idx - 360 : idx;
        const uint32_t* wp = (which ? whop : wxop) + col;
        const float2* s2 = which ? (const float2*)(hc + 16) : (const float2*)xol;
        float acc = 0.f;
#pragma unroll
        for (int p = 0; p < 60; ++p) {
          float2 xv = s2[p];
          float2 wv = __half22float2(*(const __half2*)&wp[p * 360]);
          acc += xv.x * wv.x + xv.y * wv.y;
        }
        g[idx] = acc;
      } else {
        const int jj = idx - 720;
        const int which = (jj >= 48) ? 1 : 0;
        const int col = which ? jj - 48 : jj;
        const float* W = which ? whd : wxd;
        float a = 0.f;
#pragma unroll
        for (int k = 0; k < 16; ++k) {
          float sv = which ? expf(hc[k]) : xdl[k];
          a += sv * fabsf(W[k * 48 + col]);
        }
        g2[jj] = a;
      }
    }
    __syncthreads();

    if (tid < 120) {
      float r = sigm(g[tid] + g[360 + tid] + bov[tid]);
      float z = sigm(g[120 + tid] + g[480 + tid] + bov[120 + tid]);
      float ng = tanhf(g[240 + tid] + r * g[600 + tid] + bov[240 + tid]);
      float ho = hc[16 + tid];
      hc[16 + tid] = ng + z * (ho - ng);
    } else if (tid >= 128 && tid < 144) {
      int t = tid - 128;
      float ixr = g2[t], ixi = g2[16 + t], ixn = g2[32 + t];
      float hhr = g2[48 + t], hhi = g2[64 + t], hhn = g2[80 + t];
      float br = fabsf(bdv[t]), bi = fabsf(bdv[16 + t]), bn = fabsf(bdv[32 + t]);
      float r = sigm(br * ixr * hhr);
      float z = sigm(bi * ixi * hhi);
      float sp = bn * ixn * r * hhn;
      float ng = (sp > 20.f) ? sp : log1pf(expf(sp));
      float ldp = hc[t];
      hc[t] = z * ldp + (1.f - z) * logf(ng);
    }
    __syncthreads();
  }

  if (tid < 5) {
    float a = cbv[tid];
    for (int k = 0; k < 136; ++k) a += hc[k] * cw[k * 5 + tid];
    out[(size_t)b * 5 + tid] = a;
  }
}

// ------------------------------ launch ------------------------------
extern "C" void kernel_launch(void* const* d_in, const int* in_sizes, int n_in,
                              void* d_out, int out_size, void* d_ws, size_t ws_size,
                              hipStream_t stream) {
  const float* x       = (const float*)d_in[0];
  const float* fw      = (const float*)d_in[1];
  const float* s_tri   = (const float*)d_in[2];
  const float* conv1_w = (const float*)d_in[3];
  const float* conv1_b = (const float*)d_in[4];
  const float* bn1_g   = (const float*)d_in[5];
  const float* bn1_b   = (const float*)d_in[6];
  const float* conv2_w = (const float*)d_in[7];
  const float* conv2_b = (const float*)d_in[8];
  const float* bn2_g   = (const float*)d_in[9];
  const float* bn2_b   = (const float*)d_in[10];
  const float* wx_d    = (const float*)d_in[11];
  const float* wh_d    = (const float*)d_in[12];
  const float* bias_d  = (const float*)d_in[13];
  const float* wx_o    = (const float*)d_in[14];
  const float* wh_o    = (const float*)d_in[15];
  const float* bias_o  = (const float*)d_in[16];
  const float* ode_w0  = (const float*)d_in[17];
  const float* ode_b0  = (const float*)d_in[18];
  const float* ode_w1  = (const float*)d_in[19];
  const float* ode_b1  = (const float*)d_in[20];
  const float* ode_w2  = (const float*)d_in[21];
  const float* ode_b2  = (const float*)d_in[22];
  const float* ode_w3  = (const float*)d_in[23];
  const float* ode_b3  = (const float*)d_in[24];
  const float* cls_w   = (const float*)d_in[25];
  const float* cls_b   = (const float*)d_in[26];

  float* ws = (float*)d_ws;
  float* h1  = ws;                    // 8,908,800 floats (K1->K2), then dead
  float* h3  = ws;                    // 1,075,200 floats (K4->K6)
  float* xd  = ws + 1075200;          // 51,200
  float* xo  = ws + 1126400;          // 384,000
  float* h2  = ws + 8908800;          // 7,680,000 (K2->K4), then reused by K0
  float* p1  = ws + 16588800;         // 614,400
  float* bn1 = ws + 17203200;         // 192
  float* p2  = ws + 17203392;         // 25,600
  float* bn2 = ws + 17228992;         // 32
  uint32_t* pk = (uint32_t*)(ws + 8908800);  // packed weights (dead h2 region)

  hipLaunchKernelGGL(k1_fb,   dim3(NIMG),   dim3(256), 0, stream, x, fw, s_tri, h1);
  hipLaunchKernelGGL(k2_conv1,dim3(NIMG/2), dim3(256), 0, stream, h1, conv1_w, conv1_b, h2, p1);
  hipLaunchKernelGGL(k3_bn1,  dim3(96),     dim3(256), 0, stream, p1, bn1_g, bn1_b, bn1);
  hipLaunchKernelGGL(k4_conv2,dim3(NIMG/4), dim3(256), 0, stream, h2, conv2_w, conv2_b, bn1, h3, p2);
  hipLaunchKernelGGL(k5_bn2,  dim3(16),     dim3(256), 0, stream, p2, bn2_g, bn2_b, bn2);
  hipLaunchKernelGGL(k6_oas,  dim3(NIMG/4), dim3(256), 0, stream, h3, bn2, xd, xo);
  hipLaunchKernelGGL(k0_pack, dim3((PK_TOT + 255) / 256), dim3(256), 0, stream,
                     ode_w0, ode_w1, ode_w2, ode_w3, wx_o, wh_o, pk);
  hipLaunchKernelGGL(k7_scan, dim3(BB),     dim3(512), 0, stream,
                     xd, xo, wx_d, wh_d, bias_d, bias_o, pk,
                     ode_b0, ode_b1, ode_b2, ode_b3, cls_w, cls_b, (float*)d_out);
}

// Round 4
// 6033.089 us; speedup vs baseline: 2.9511x; 2.9511x over previous
//
#include <hip/hip_runtime.h>
#include <hip/hip_fp16.h>
#include <math.h>

// ---------------------------------------------------------------------------
// ODERGRU pipeline for MI355X.
//  K1: einsum -> h1 (3200,96,29)
//  K2: conv1d 96->96 k5 + bias -> h2 + BN partials
//  K3: BN1 reduce (parallel, f64 tree)
//  K4: conv1d 96->16 k5 (BN1+lrelu on load) -> h3 + BN2 partials
//  K5: BN2 reduce
//  K6: OAS + Cholesky -> x_d, x_o
//  K0: pack ODE/GRU weights f32 -> f16x2 (into dead h2 region)
//  K7: per-batch-row scan; 1024 thr (16 waves = 4/SIMD TLP); K-split x4 with
//      in-wave shfl_xor combine; f16 weights streamed from L2 (NO big arrays)
// ---------------------------------------------------------------------------

#define BB 64
#define NIMG 3200

__device__ __forceinline__ float sigm(float x) { return 1.f / (1.f + expf(-x)); }

// ------------------------------ K1: filterbank ------------------------------
__global__ __launch_bounds__(256) void k1_fb(const float* __restrict__ x,
                                             const float* __restrict__ fw,
                                             const float* __restrict__ st,
                                             float* __restrict__ h1) {
  __shared__ __align__(16) float ws[129 * 32];
  __shared__ __align__(16) float xs[129 * 32];
  const int tid = threadIdx.x;
  const int n = blockIdx.x;
  const float* xp = x + (size_t)n * 11223;

  for (int i = tid; i < 4128; i += 256) ws[i] = fw[i] * st[i];

  float acc[4][4];
#pragma unroll
  for (int i = 0; i < 4; ++i)
#pragma unroll
    for (int j = 0; j < 4; ++j) acc[i][j] = 0.f;

  const int c = tid / 64;
  const int rem = tid % 64;
  const int m0 = (rem / 8) * 4;
  const int t0 = (rem % 8) * 4;

  for (int fc = 0; fc < 3; ++fc) {
    __syncthreads();
    for (int i = tid; i < 3741; i += 256) {
      int cc = i / 1247;
      int r = i - cc * 1247;
      int f = r / 29;
      int t = r - f * 29;
      xs[(cc * 43 + f) * 32 + t] = xp[cc * 3741 + (fc * 43 + f) * 29 + t];
    }
    for (int i = tid; i < 129; i += 256) {
      xs[i * 32 + 29] = 0.f; xs[i * 32 + 30] = 0.f; xs[i * 32 + 31] = 0.f;
    }
    __syncthreads();
    if (tid < 192) {
      const float* xb = xs + (c * 43) * 32 + t0;
      const float* wb = ws + (fc * 43) * 32 + m0;
      for (int f = 0; f < 43; ++f) {
        float4 xv = *(const float4*)(xb + f * 32);
        float4 wv = *(const float4*)(wb + f * 32);
        float xa[4] = {xv.x, xv.y, xv.z, xv.w};
        float wa[4] = {wv.x, wv.y, wv.z, wv.w};
#pragma unroll
        for (int i = 0; i < 4; ++i)
#pragma unroll
          for (int j = 0; j < 4; ++j) acc[i][j] += wa[i] * xa[j];
      }
    }
  }
  if (tid < 192) {
    const int nt = (t0 == 28) ? 1 : 4;
    for (int i = 0; i < 4; ++i)
      for (int j = 0; j < nt; ++j)
        h1[(size_t)n * 2784 + (size_t)(c * 32 + m0 + i) * 29 + (t0 + j)] = acc[i][j];
  }
}

// ------------------------------ K2: conv1 ------------------------------
__global__ __launch_bounds__(256) void k2_conv1(const float* __restrict__ h1,
                                                const float* __restrict__ w,
                                                const float* __restrict__ bias,
                                                float* __restrict__ h2,
                                                float* __restrict__ part1) {
  __shared__ __align__(16) float ins[2 * 96 * 32];
  __shared__ __align__(16) float wls[96 * 81];
  const int tid = threadIdx.x;
  const int wg = blockIdx.x;

  for (int i = tid; i < 2 * 2784; i += 256) {
    int img = i / 2784;
    int e = i - img * 2784;
    int ci = e / 29;
    int t = e - ci * 29;
    ins[img * 3072 + ci * 32 + t] = h1[(size_t)(wg * 2 + img) * 2784 + e];
  }

  const int img = tid / 96;
  const int co = tid - img * 96;
  float acc[25];
#pragma unroll
  for (int t = 0; t < 25; ++t) acc[t] = 0.f;

  for (int cc = 0; cc < 6; ++cc) {
    __syncthreads();
    for (int i = tid; i < 7680; i += 256) {
      int cw = i / 80;
      int r = i - cw * 80;
      wls[cw * 81 + r] = w[cw * 480 + cc * 80 + r];
    }
    __syncthreads();
    if (tid < 192) {
      for (int ci = 0; ci < 16; ++ci) {
        float xv[29];
#pragma unroll
        for (int j = 0; j < 29; ++j) xv[j] = ins[img * 3072 + (cc * 16 + ci) * 32 + j];
        float wv[5];
#pragma unroll
        for (int d = 0; d < 5; ++d) wv[d] = wls[co * 81 + ci * 5 + d];
#pragma unroll
        for (int t = 0; t < 25; ++t) {
          float s = acc[t];
#pragma unroll
          for (int d = 0; d < 5; ++d) s += xv[t + d] * wv[d];
          acc[t] = s;
        }
      }
    }
  }
  if (tid < 192) {
    const int n = wg * 2 + img;
    const float bval = bias[co];
    float s1 = 0.f, s2 = 0.f;
    for (int t = 0; t < 25; ++t) {
      float v = acc[t] + bval;
      h2[(size_t)n * 2400 + co * 25 + t] = v;
      s1 += v;
      s2 += v * v;
    }
    part1[((size_t)n * 96 + co) * 2 + 0] = s1;
    part1[((size_t)n * 96 + co) * 2 + 1] = s2;
  }
}

// ------------------------------ K3/K5: BN reduce (parallel) -----------------
__global__ __launch_bounds__(256) void k3_bn1(const float* __restrict__ part,
                                              const float* __restrict__ gg,
                                              const float* __restrict__ be,
                                              float* __restrict__ ab) {
  __shared__ double sd[256], sq[256];
  const int c = blockIdx.x;       // 96
  const int t = threadIdx.x;
  double s = 0.0, q = 0.0;
  for (int n = t; n < NIMG; n += 256) {
    s += (double)part[((size_t)n * 96 + c) * 2 + 0];
    q += (double)part[((size_t)n * 96 + c) * 2 + 1];
  }
  sd[t] = s; sq[t] = q;
  __syncthreads();
  for (int off = 128; off > 0; off >>= 1) {
    if (t < off) { sd[t] += sd[t + off]; sq[t] += sq[t + off]; }
    __syncthreads();
  }
  if (t == 0) {
    double mu = sd[0] / 80000.0;
    double var = sq[0] / 80000.0 - mu * mu;
    float A = (float)((double)gg[c] / sqrt(var + 1e-5));
    ab[c * 2 + 0] = A;
    ab[c * 2 + 1] = (float)((double)be[c] - mu * (double)A);
  }
}

__global__ __launch_bounds__(256) void k5_bn2(const float* __restrict__ part,
                                              const float* __restrict__ gg,
                                              const float* __restrict__ be,
                                              float* __restrict__ ab) {
  __shared__ double sd[256], sq[256];
  const int c = blockIdx.x;       // 16
  const int t = threadIdx.x;
  double s = 0.0, q = 0.0;
  for (int n = t; n < 800; n += 256) {
    s += (double)part[((size_t)n * 16 + c) * 2 + 0];
    q += (double)part[((size_t)n * 16 + c) * 2 + 1];
  }
  sd[t] = s; sq[t] = q;
  __syncthreads();
  for (int off = 128; off > 0; off >>= 1) {
    if (t < off) { sd[t] += sd[t + off]; sq[t] += sq[t + off]; }
    __syncthreads();
  }
  if (t == 0) {
    double mu = sd[0] / 67200.0;
    double var = sq[0] / 67200.0 - mu * mu;
    float A = (float)((double)gg[c] / sqrt(var + 1e-5));
    ab[c * 2 + 0] = A;
    ab[c * 2 + 1] = (float)((double)be[c] - mu * (double)A);
  }
}

// ------------------------------ K4: conv2 ------------------------------
__global__ __launch_bounds__(256) void k4_conv2(const float* __restrict__ h2,
                                                const float* __restrict__ w,
                                                const float* __restrict__ bias,
                                                const float* __restrict__ bn1,
                                                float* __restrict__ h3,
                                                float* __restrict__ part2) {
  __shared__ __align__(16) float ins[4 * 96 * 26];
  __shared__ __align__(16) float wls[16 * 241];
  __shared__ float A1s[96], B1s[96];
  __shared__ float red[16 * 16 * 2];
  const int tid = threadIdx.x;
  const int wg = blockIdx.x;

  if (tid < 96) {
    A1s[tid] = bn1[tid * 2 + 0];
    B1s[tid] = bn1[tid * 2 + 1];
  }
  __syncthreads();
  for (int i = tid; i < 9600; i += 256) {
    int img = i / 2400;
    int e = i - img * 2400;
    int ci = e / 25;
    int t = e - ci * 25;
    float v = h2[(size_t)(wg * 4 + img) * 2400 + e];
    v = A1s[ci] * v + B1s[ci];
    v = (v >= 0.f) ? v : 0.01f * v;
    ins[img * 2496 + ci * 26 + t] = v;
  }
  for (int i = tid; i < 4 * 96; i += 256) ins[(i / 96) * 2496 + (i % 96) * 26 + 25] = 0.f;

  const int img = tid >> 6;
  const int co = (tid >> 2) & 15;
  const int tg = tid & 3;
  const int t0s[4] = {0, 6, 11, 16};
  const int t0 = t0s[tg];
  const int tl = (tg == 0) ? 6 : 5;
  float acc[6] = {0.f, 0.f, 0.f, 0.f, 0.f, 0.f};

  for (int cc = 0; cc < 2; ++cc) {
    __syncthreads();
    for (int i = tid; i < 3840; i += 256) {
      int cw = i / 240;
      int r = i - cw * 240;
      wls[cw * 241 + r] = w[cw * 480 + cc * 240 + r];
    }
    __syncthreads();
    for (int ci = 0; ci < 48; ++ci) {
      float xv[10];
#pragma unroll
      for (int j = 0; j < 10; ++j) xv[j] = ins[img * 2496 + (cc * 48 + ci) * 26 + t0 + j];
      float wv[5];
#pragma unroll
      for (int d = 0; d < 5; ++d) wv[d] = wls[co * 241 + ci * 5 + d];
#pragma unroll
      for (int t = 0; t < 6; ++t) {
        float s = acc[t];
#pragma unroll
        for (int d = 0; d < 5; ++d) s += xv[t + d] * wv[d];
        acc[t] = s;
      }
    }
  }
  const float bval = bias[co];
  float s1 = 0.f, s2 = 0.f;
  const int n = wg * 4 + img;
  for (int t = 0; t < 6; ++t) {
    if (t < tl) {
      float v = acc[t] + bval;
      h3[(size_t)n * 336 + co * 21 + t0 + t] = v;
      s1 += v;
      s2 += v * v;
    }
  }
  red[(co * 16 + img * 4 + tg) * 2 + 0] = s1;
  red[(co * 16 + img * 4 + tg) * 2 + 1] = s2;
  __syncthreads();
  if (tid < 16) {
    float s = 0.f, q = 0.f;
    for (int k = 0; k < 16; ++k) {
      s += red[(tid * 16 + k) * 2 + 0];
      q += red[(tid * 16 + k) * 2 + 1];
    }
    part2[((size_t)wg * 16 + tid) * 2 + 0] = s;
    part2[((size_t)wg * 16 + tid) * 2 + 1] = q;
  }
}

// ------------------------------ K6: OAS + Cholesky ------------------------------
__global__ __launch_bounds__(256) void k6_oas(const float* __restrict__ h3,
                                              const float* __restrict__ bn2,
                                              float* __restrict__ xd,
                                              float* __restrict__ xo) {
  __shared__ float X[4][21 * 17 + 3];
  __shared__ float A[4][16 * 17];
  __shared__ float mcol[4][16];
  const int tid = threadIdx.x;
  const int wid = tid >> 6;
  const int lane = tid & 63;
  const int n = blockIdx.x * 4 + wid;
  const float* hp = h3 + (size_t)n * 336;

  for (int e = lane; e < 336; e += 64) {
    int c = e / 21;
    int t = e - c * 21;
    float v = hp[e];
    v = bn2[c * 2 + 0] * v + bn2[c * 2 + 1];
    v = (v >= 0.f) ? v : 0.01f * v;
    X[wid][t * 17 + c] = v;
  }
  __syncthreads();
  if (lane < 16) {
    float s = 0.f;
    for (int t = 0; t < 21; ++t) s += X[wid][t * 17 + lane];
    mcol[wid][lane] = s * (1.f / 21.f);
  }
  __syncthreads();
  for (int e = lane; e < 336; e += 64) {
    int t = e / 16;
    int c = e - t * 16;
    X[wid][t * 17 + c] -= mcol[wid][c];
  }
  __syncthreads();

  float tr_p = 0.f, al_p = 0.f;
  float ent[3];
  int ei[3], ej[3], ne = 0;
  for (int e = lane; e < 136; e += 64) {
    int i = 0, e2 = e;
    while (e2 >= 16 - i) { e2 -= 16 - i; i++; }
    int j = i + e2;
    float s = 0.f;
    for (int t = 0; t < 21; ++t) s += X[wid][t * 17 + i] * X[wid][t * 17 + j];
    s *= (1.f / 20.f);
    ent[ne] = s; ei[ne] = i; ej[ne] = j; ne++;
    if (i == j) tr_p += s;
    al_p += s * s * ((i == j) ? 1.f : 2.f);
  }
  for (int m = 1; m < 64; m <<= 1) {
    tr_p += __shfl_xor(tr_p, m);
    al_p += __shfl_xor(al_p, m);
  }
  const float mu = tr_p * (1.f / 16.f);
  const float alpha = al_p * (1.f / 256.f);
  const float num = alpha + mu * mu;
  const float den = 22.f * (alpha - mu * mu * (1.f / 16.f));
  const float shr = (den == 0.f) ? 1.f : fminf(num / den, 1.f);
  for (int q = 0; q < ne; ++q) {
    float c = (1.f - shr) * ent[q] + ((ei[q] == ej[q]) ? shr * mu : 0.f);
    A[wid][ei[q] * 17 + ej[q]] = c;
    A[wid][ej[q] * 17 + ei[q]] = c;
  }
  __syncthreads();

  for (int k = 0; k < 16; ++k) {
    float akk = A[wid][k * 17 + k];
    __syncthreads();
    float d = sqrtf(akk);
    float rd = 1.f / d;
    if (lane == k) A[wid][k * 17 + k] = d;
    if (lane > k && lane < 16) A[wid][lane * 17 + k] *= rd;
    __syncthreads();
    if (lane > k && lane < 16) {
      float Lik = A[wid][lane * 17 + k];
      for (int j = k + 1; j <= lane; ++j) A[wid][lane * 17 + j] -= Lik * A[wid][j * 17 + k];
    }
    __syncthreads();
  }
  if (lane < 16) xd[(size_t)n * 16 + lane] = A[wid][lane * 17 + lane];
  for (int p = lane; p < 120; p += 64) {
    int i = 1, p2 = p;
    while (p2 >= i) { p2 -= i; i++; }
    xo[(size_t)n * 120 + p] = A[wid][i * 17 + p2];
  }
}

// ------------------------------ K0: weight pack (f32 -> f16x2) --------------
// pair p packs K rows (2p, 2p+1).
// layout: [0,17408) w0p [p*256+j]  (68 pairs x 256)
//         [17408,50176) w1p        (128 x 256)
//         [50176,82944) w2p        (128 x 256)
//         [82944,100352) w3p [p*136+c] (128 x 136)
//         [100352,121952) wxop [p*360+c] (60 x 360)
//         [121952,143552) whop       (60 x 360)
#define PK_TOT 143552
__global__ __launch_bounds__(256) void k0_pack(const float* __restrict__ w0,
                                               const float* __restrict__ w1,
                                               const float* __restrict__ w2,
                                               const float* __restrict__ w3,
                                               const float* __restrict__ wxo,
                                               const float* __restrict__ who,
                                               uint32_t* __restrict__ dst) {
  int i = blockIdx.x * 256 + threadIdx.x;
  if (i >= PK_TOT) return;
  float a, bf;
  if (i < 17408) {
    int p = i >> 8, j = i & 255;
    a = w0[(2 * p) * 256 + j]; bf = w0[(2 * p + 1) * 256 + j];
  } else if (i < 50176) {
    int t = i - 17408; int p = t >> 8, j = t & 255;
    a = w1[(2 * p) * 256 + j]; bf = w1[(2 * p + 1) * 256 + j];
  } else if (i < 82944) {
    int t = i - 50176; int p = t >> 8, j = t & 255;
    a = w2[(2 * p) * 256 + j]; bf = w2[(2 * p + 1) * 256 + j];
  } else if (i < 100352) {
    int t = i - 82944; int p = t / 136, c = t - p * 136;
    a = w3[(2 * p) * 136 + c]; bf = w3[(2 * p + 1) * 136 + c];
  } else if (i < 121952) {
    int t = i - 100352; int p = t / 360, c = t - p * 360;
    a = wxo[(2 * p) * 360 + c]; bf = wxo[(2 * p + 1) * 360 + c];
  } else {
    int t = i - 121952; int p = t / 360, c = t - p * 360;
    a = who[(2 * p) * 360 + c]; bf = who[(2 * p + 1) * 360 + c];
  }
  __half2 h = __floats2half2_rn(a, bf);
  dst[i] = *reinterpret_cast<uint32_t*>(&h);
}

// ------------------------------ K7: scan (1024 thr, K-split x4, streamed) ---
// tid -> (j = tid>>2 output col, h = tid&3 K-quarter). Weights streamed from
// L2 each use (f16x2 u32 loads, coalesced across j). No per-thread arrays.
// Partial sums combined with two in-wave shfl_xor (lanes 4j..4j+3).
__global__ __launch_bounds__(1024) void k7_scan(
    const float* __restrict__ xdv, const float* __restrict__ xov,
    const float* __restrict__ wxd, const float* __restrict__ whd,
    const float* __restrict__ bdv, const float* __restrict__ bov,
    const uint32_t* __restrict__ pk,
    const float* __restrict__ b0, const float* __restrict__ b1,
    const float* __restrict__ b2, const float* __restrict__ b3,
    const float* __restrict__ cw, const float* __restrict__ cbv,
    float* __restrict__ out) {
  __shared__ __align__(16) float hc[136];
  __shared__ __align__(16) float bufA[256];
  __shared__ __align__(16) float bufB[256];
  __shared__ __align__(16) float xdl[16];
  __shared__ __align__(16) float xol[120];
  __shared__ __align__(16) float g[720];
  __shared__ __align__(16) float g2[96];
  const int tid = threadIdx.x;
  const int j = tid >> 2;     // 0..255 output column
  const int h = tid & 3;      // K quarter
  const int b = blockIdx.x;

  const uint32_t* w0p  = pk;            // [68][256]  pairs
  const uint32_t* w1p  = pk + 17408;    // [128][256]
  const uint32_t* w2p  = pk + 50176;    // [128][256]
  const uint32_t* w3p  = pk + 82944;    // [128][136]
  const uint32_t* wxop = pk + 100352;   // [60][360]
  const uint32_t* whop = pk + 121952;   // [60][360]

  const float bj0 = b0[j], bj1 = b1[j], bj2 = b2[j];
  const float bj3 = (j < 136) ? b3[j] : 0.f;

  if (tid < 136) hc[tid] = 0.f;
  __syncthreads();

#pragma unroll 1
  for (int s = 0; s < 50; ++s) {
    if (tid < 16) xdl[tid] = xdv[(size_t)(b * 50 + s) * 16 + tid];
    else if (tid < 136) xol[tid - 16] = xov[(size_t)(b * 50 + s) * 120 + (tid - 16)];
    // consumed in the gate phase (after several barriers) — no barrier needed

#pragma unroll 1
    for (int e = 0; e < 4; ++e) {
      // L1: hc(136) -> bufA(256) tanh. 68 k-pairs, interleaved p = h + 4c.
      {
        float acc = 0.f;
        const float2* h2v = (const float2*)hc;
        const uint32_t* wp = w0p + j;
#pragma unroll
        for (int c = 0; c < 17; ++c) {
          const int p = h + 4 * c;
          float2 xv = h2v[p];
          float2 wv = __half22float2(*(const __half2*)&wp[p * 256]);
          acc += xv.x * wv.x + xv.y * wv.y;
        }
        acc += __shfl_xor(acc, 1);
        acc += __shfl_xor(acc, 2);
        if (h == 0) bufA[j] = tanhf(acc + bj0);
      }
      __syncthreads();
      // L2: bufA -> bufB tanh. 128 pairs; quarter h -> pairs [32h,32h+32).
      {
        float acc = 0.f;
        const float4* a4 = (const float4*)bufA;
        const uint32_t* wp = w1p + j;
#pragma unroll
        for (int c = 0; c < 16; ++c) {
          float4 xv = a4[16 * h + c];
          const int p = 32 * h + 2 * c;
          float2 wa = __half22float2(*(const __half2*)&wp[p * 256]);
          float2 wb = __half22float2(*(const __half2*)&wp[(p + 1) * 256]);
          acc += xv.x * wa.x + xv.y * wa.y + xv.z * wb.x + xv.w * wb.y;
        }
        acc += __shfl_xor(acc, 1);
        acc += __shfl_xor(acc, 2);
        if (h == 0) bufB[j] = tanhf(acc + bj1);
      }
      __syncthreads();
      // L3: bufB -> bufA tanh
      {
        float acc = 0.f;
        const float4* a4 = (const float4*)bufB;
        const uint32_t* wp = w2p + j;
#pragma unroll
        for (int c = 0; c < 16; ++c) {
          float4 xv = a4[16 * h + c];
          const int p = 32 * h + 2 * c;
          float2 wa = __half22float2(*(const __half2*)&wp[p * 256]);
          float2 wb = __half22float2(*(const __half2*)&wp[(p + 1) * 256]);
          acc += xv.x * wa.x + xv.y * wa.y + xv.z * wb.x + xv.w * wb.y;
        }
        acc += __shfl_xor(acc, 1);
        acc += __shfl_xor(acc, 2);
        if (h == 0) bufA[j] = tanhf(acc + bj2);
      }
      __syncthreads();
      // L4: bufA -> hc += 0.25*(w3^T a + b3); only j<136 columns exist.
      if (j < 136) {
        float acc = 0.f;
        const float4* a4 = (const float4*)bufA;
        const uint32_t* wp = w3p + j;
#pragma unroll
        for (int c = 0; c < 16; ++c) {
          float4 xv = a4[16 * h + c];
          const int p = 32 * h + 2 * c;
          float2 wa = __half22float2(*(const __half2*)&wp[p * 136]);
          float2 wb = __half22float2(*(const __half2*)&wp[(p + 1) * 136]);
          acc += xv.x * wa.x + xv.y * wa.y + xv.z * wb.x + xv.w * wb.y;
        }
        acc += __shfl_xor(acc, 1);
        acc += __shfl_xor(acc, 2);
        if (h == 0) hc[j] += 0.25f * (acc + bj3);
      }
      __syncthreads();
    }

    // Gates: 720 o-dots (K=120, packed f16) + 96 d-dots (K=16, f32). tid<816.
    if (tid < 816) {
      if (tid < 720) {
        const int which = (tid >= 360) ? 1 : 0;
        const int col = which ? tid - 360 : tid;
        const uint32_t* wp = (which ? whop : wxop) + col;
        const float2* s2 = which ? (const float2*)(hc + 16) : (const float2*)xol;
        float acc = 0.f;
#pragma unroll
        for (int p = 0; p < 60; ++p) {
          float2 xv = s2[p];
          float2 wv = __half22float2(*(const __half2*)&wp[p * 360]);
          acc += xv.x * wv.x + xv.y * wv.y;
        }
        g[tid] = acc;
      } else {
        const int jj = tid - 720;
        const int which = (jj >= 48) ? 1 : 0;
        const int col = which ? jj - 48 : jj;
        const float* W = which ? whd : wxd;
        float a = 0.f;
#pragma unroll
        for (int k = 0; k < 16; ++k) {
          float sv = which ? expf(hc[k]) : xdl[k];
          a += sv * fabsf(W[k * 48 + col]);
        }
        g2[jj] = a;
      }
    }
    __syncthreads();

    if (tid < 120) {
      float r = sigm(g[tid] + g[360 + tid] + bov[tid]);
      float z = sigm(g[120 + tid] + g[480 + tid] + bov[120 + tid]);
      float ng = tanhf(g[240 + tid] + r * g[600 + tid] + bov[240 + tid]);
      float ho = hc[16 + tid];
      hc[16 + tid] = ng + z * (ho - ng);
    } else if (tid >= 128 && tid < 144) {
      int t = tid - 128;
      float ixr = g2[t], ixi = g2[16 + t], ixn = g2[32 + t];
      float hhr = g2[48 + t], hhi = g2[64 + t], hhn = g2[80 + t];
      float br = fabsf(bdv[t]), bi = fabsf(bdv[16 + t]), bn = fabsf(bdv[32 + t]);
      float r = sigm(br * ixr * hhr);
      float z = sigm(bi * ixi * hhi);
      float sp = bn * ixn * r * hhn;
      float ng = (sp > 20.f) ? sp : log1pf(expf(sp));
      float ldp = hc[t];
      hc[t] = z * ldp + (1.f - z) * logf(ng);
    }
    __syncthreads();
  }

  if (tid < 5) {
    float a = cbv[tid];
    for (int k = 0; k < 136; ++k) a += hc[k] * cw[k * 5 + tid];
    out[(size_t)b * 5 + tid] = a;
  }
}

// ------------------------------ launch ------------------------------
extern "C" void kernel_launch(void* const* d_in, const int* in_sizes, int n_in,
                              void* d_out, int out_size, void* d_ws, size_t ws_size,
                              hipStream_t stream) {
  const float* x       = (const float*)d_in[0];
  const float* fw      = (const float*)d_in[1];
  const float* s_tri   = (const float*)d_in[2];
  const float* conv1_w = (const float*)d_in[3];
  const float* conv1_b = (const float*)d_in[4];
  const float* bn1_g   = (const float*)d_in[5];
  const float* bn1_b   = (const float*)d_in[6];
  const float* conv2_w = (const float*)d_in[7];
  const float* conv2_b = (const float*)d_in[8];
  const float* bn2_g   = (const float*)d_in[9];
  const float* bn2_b   = (const float*)d_in[10];
  const float* wx_d    = (const float*)d_in[11];
  const float* wh_d    = (const float*)d_in[12];
  const float* bias_d  = (const float*)d_in[13];
  const float* wx_o    = (const float*)d_in[14];
  const float* wh_o    = (const float*)d_in[15];
  const float* bias_o  = (const float*)d_in[16];
  const float* ode_w0  = (const float*)d_in[17];
  const float* ode_b0  = (const float*)d_in[18];
  const float* ode_w1  = (const float*)d_in[19];
  const float* ode_b1  = (const float*)d_in[20];
  const float* ode_w2  = (const float*)d_in[21];
  const float* ode_b2  = (const float*)d_in[22];
  const float* ode_w3  = (const float*)d_in[23];
  const float* ode_b3  = (const float*)d_in[24];
  const float* cls_w   = (const float*)d_in[25];
  const float* cls_b   = (const float*)d_in[26];

  float* ws = (float*)d_ws;
  float* h1  = ws;                    // 8,908,800 floats (K1->K2), then dead
  float* h3  = ws;                    // 1,075,200 floats (K4->K6)
  float* xd  = ws + 1075200;          // 51,200
  float* xo  = ws + 1126400;          // 384,000
  float* h2  = ws + 8908800;          // 7,680,000 (K2->K4), then reused by K0
  float* p1  = ws + 16588800;         // 614,400
  float* bn1 = ws + 17203200;         // 192
  float* p2  = ws + 17203392;         // 25,600
  float* bn2 = ws + 17228992;         // 32
  uint32_t* pk = (uint32_t*)(ws + 8908800);  // packed weights (dead h2 region)

  hipLaunchKernelGGL(k1_fb,   dim3(NIMG),   dim3(256), 0, stream, x, fw, s_tri, h1);
  hipLaunchKernelGGL(k2_conv1,dim3(NIMG/2), dim3(256), 0, stream, h1, conv1_w, conv1_b, h2, p1);
  hipLaunchKernelGGL(k3_bn1,  dim3(96),     dim3(256), 0, stream, p1, bn1_g, bn1_b, bn1);
  hipLaunchKernelGGL(k4_conv2,dim3(NIMG/4), dim3(256), 0, stream, h2, conv2_w, conv2_b, bn1, h3, p2);
  hipLaunchKernelGGL(k5_bn2,  dim3(16),     dim3(256), 0, stream, p2, bn2_g, bn2_b, bn2);
  hipLaunchKernelGGL(k6_oas,  dim3(NIMG/4), dim3(256), 0, stream, h3, bn2, xd, xo);
  hipLaunchKernelGGL(k0_pack, dim3((PK_TOT + 255) / 256), dim3(256), 0, stream,
                     ode_w0, ode_w1, ode_w2, ode_w3, wx_o, wh_o, pk);
  hipLaunchKernelGGL(k7_scan, dim3(BB),     dim3(1024), 0, stream,
                     xd, xo, wx_d, wh_d, bias_d, bias_o, pk,
                     ode_b0, ode_b1, ode_b2, ode_b3, cls_w, cls_b, (float*)d_out);
}

// Round 5
// 2002.776 us; speedup vs baseline: 8.8896x; 3.0124x over previous
//
#include <hip/hip_runtime.h>
#include <math.h>

// ---------------------------------------------------------------------------
// ODERGRU pipeline for MI355X.
//  K1: einsum -> h1 (3200,96,29)
//  K2: conv1d 96->96 k5 + bias -> h2 + BN partials
//  K3: BN1 reduce   K5: BN2 reduce  (f64 tree)
//  K4: conv1d 96->16 k5 (BN1+lrelu on load) -> h3 + BN2 partials
//  K6: OAS + Cholesky -> x_d, x_o
//  K0: pack ODE/GRU weights f32 -> f16 B-fragments (MFMA lane order)
//  K7: 4 blocks x 16 rows; MFMA 16x16x32_f16 for ODE MLP and o-gates;
//      activations ping-pong in swizzled LDS; d-gates full f32 VALU.
// ---------------------------------------------------------------------------

#define BB 64
#define NIMG 3200

typedef _Float16 f16;
typedef _Float16 f16x8 __attribute__((ext_vector_type(8)));
typedef float f32x4 __attribute__((ext_vector_type(4)));

__device__ __forceinline__ float sigm(float x) { return 1.f / (1.f + expf(-x)); }

// pk region offsets (u32 units)
#define OFF_W0  0
#define OFF_W1  20480
#define OFF_W2  53248
#define OFF_W3  86016
#define OFF_GRZ 104448
#define OFF_GNX 135168
#define OFF_GNH 143360
#define PK2_TOT 151552

// ------------------------------ K1: filterbank ------------------------------
__global__ __launch_bounds__(256) void k1_fb(const float* __restrict__ x,
                                             const float* __restrict__ fw,
                                             const float* __restrict__ st,
                                             float* __restrict__ h1) {
  __shared__ __align__(16) float ws[129 * 32];
  __shared__ __align__(16) float xs[129 * 32];
  const int tid = threadIdx.x;
  const int n = blockIdx.x;
  const float* xp = x + (size_t)n * 11223;

  for (int i = tid; i < 4128; i += 256) ws[i] = fw[i] * st[i];

  float acc[4][4];
#pragma unroll
  for (int i = 0; i < 4; ++i)
#pragma unroll
    for (int j = 0; j < 4; ++j) acc[i][j] = 0.f;

  const int c = tid / 64;
  const int rem = tid % 64;
  const int m0 = (rem / 8) * 4;
  const int t0 = (rem % 8) * 4;

  for (int fc = 0; fc < 3; ++fc) {
    __syncthreads();
    for (int i = tid; i < 3741; i += 256) {
      int cc = i / 1247;
      int r = i - cc * 1247;
      int f = r / 29;
      int t = r - f * 29;
      xs[(cc * 43 + f) * 32 + t] = xp[cc * 3741 + (fc * 43 + f) * 29 + t];
    }
    for (int i = tid; i < 129; i += 256) {
      xs[i * 32 + 29] = 0.f; xs[i * 32 + 30] = 0.f; xs[i * 32 + 31] = 0.f;
    }
    __syncthreads();
    if (tid < 192) {
      const float* xb = xs + (c * 43) * 32 + t0;
      const float* wb = ws + (fc * 43) * 32 + m0;
      for (int f = 0; f < 43; ++f) {
        float4 xv = *(const float4*)(xb + f * 32);
        float4 wv = *(const float4*)(wb + f * 32);
        float xa[4] = {xv.x, xv.y, xv.z, xv.w};
        float wa[4] = {wv.x, wv.y, wv.z, wv.w};
#pragma unroll
        for (int i = 0; i < 4; ++i)
#pragma unroll
          for (int j = 0; j < 4; ++j) acc[i][j] += wa[i] * xa[j];
      }
    }
  }
  if (tid < 192) {
    const int nt = (t0 == 28) ? 1 : 4;
    for (int i = 0; i < 4; ++i)
      for (int j = 0; j < nt; ++j)
        h1[(size_t)n * 2784 + (size_t)(c * 32 + m0 + i) * 29 + (t0 + j)] = acc[i][j];
  }
}

// ------------------------------ K2: conv1 ------------------------------
__global__ __launch_bounds__(256) void k2_conv1(const float* __restrict__ h1,
                                                const float* __restrict__ w,
                                                const float* __restrict__ bias,
                                                float* __restrict__ h2,
                                                float* __restrict__ part1) {
  __shared__ __align__(16) float ins[2 * 96 * 32];
  __shared__ __align__(16) float wls[96 * 81];
  const int tid = threadIdx.x;
  const int wg = blockIdx.x;

  for (int i = tid; i < 2 * 2784; i += 256) {
    int img = i / 2784;
    int e = i - img * 2784;
    int ci = e / 29;
    int t = e - ci * 29;
    ins[img * 3072 + ci * 32 + t] = h1[(size_t)(wg * 2 + img) * 2784 + e];
  }

  const int img = tid / 96;
  const int co = tid - img * 96;
  float acc[25];
#pragma unroll
  for (int t = 0; t < 25; ++t) acc[t] = 0.f;

  for (int cc = 0; cc < 6; ++cc) {
    __syncthreads();
    for (int i = tid; i < 7680; i += 256) {
      int cw = i / 80;
      int r = i - cw * 80;
      wls[cw * 81 + r] = w[cw * 480 + cc * 80 + r];
    }
    __syncthreads();
    if (tid < 192) {
      for (int ci = 0; ci < 16; ++ci) {
        float xv[29];
#pragma unroll
        for (int j = 0; j < 29; ++j) xv[j] = ins[img * 3072 + (cc * 16 + ci) * 32 + j];
        float wv[5];
#pragma unroll
        for (int d = 0; d < 5; ++d) wv[d] = wls[co * 81 + ci * 5 + d];
#pragma unroll
        for (int t = 0; t < 25; ++t) {
          float s = acc[t];
#pragma unroll
          for (int d = 0; d < 5; ++d) s += xv[t + d] * wv[d];
          acc[t] = s;
        }
      }
    }
  }
  if (tid < 192) {
    const int n = wg * 2 + img;
    const float bval = bias[co];
    float s1 = 0.f, s2 = 0.f;
    for (int t = 0; t < 25; ++t) {
      float v = acc[t] + bval;
      h2[(size_t)n * 2400 + co * 25 + t] = v;
      s1 += v;
      s2 += v * v;
    }
    part1[((size_t)n * 96 + co) * 2 + 0] = s1;
    part1[((size_t)n * 96 + co) * 2 + 1] = s2;
  }
}

// ------------------------------ K3/K5: BN reduce -----------------------------
__global__ __launch_bounds__(256) void k3_bn1(const float* __restrict__ part,
                                              const float* __restrict__ gg,
                                              const float* __restrict__ be,
                                              float* __restrict__ ab) {
  __shared__ double sd[256], sq[256];
  const int c = blockIdx.x;
  const int t = threadIdx.x;
  double s = 0.0, q = 0.0;
  for (int n = t; n < NIMG; n += 256) {
    s += (double)part[((size_t)n * 96 + c) * 2 + 0];
    q += (double)part[((size_t)n * 96 + c) * 2 + 1];
  }
  sd[t] = s; sq[t] = q;
  __syncthreads();
  for (int off = 128; off > 0; off >>= 1) {
    if (t < off) { sd[t] += sd[t + off]; sq[t] += sq[t + off]; }
    __syncthreads();
  }
  if (t == 0) {
    double mu = sd[0] / 80000.0;
    double var = sq[0] / 80000.0 - mu * mu;
    float A = (float)((double)gg[c] / sqrt(var + 1e-5));
    ab[c * 2 + 0] = A;
    ab[c * 2 + 1] = (float)((double)be[c] - mu * (double)A);
  }
}

__global__ __launch_bounds__(256) void k5_bn2(const float* __restrict__ part,
                                              const float* __restrict__ gg,
                                              const float* __restrict__ be,
                                              float* __restrict__ ab) {
  __shared__ double sd[256], sq[256];
  const int c = blockIdx.x;
  const int t = threadIdx.x;
  double s = 0.0, q = 0.0;
  for (int n = t; n < 800; n += 256) {
    s += (double)part[((size_t)n * 16 + c) * 2 + 0];
    q += (double)part[((size_t)n * 16 + c) * 2 + 1];
  }
  sd[t] = s; sq[t] = q;
  __syncthreads();
  for (int off = 128; off > 0; off >>= 1) {
    if (t < off) { sd[t] += sd[t + off]; sq[t] += sq[t + off]; }
    __syncthreads();
  }
  if (t == 0) {
    double mu = sd[0] / 67200.0;
    double var = sq[0] / 67200.0 - mu * mu;
    float A = (float)((double)gg[c] / sqrt(var + 1e-5));
    ab[c * 2 + 0] = A;
    ab[c * 2 + 1] = (float)((double)be[c] - mu * (double)A);
  }
}

// ------------------------------ K4: conv2 ------------------------------
__global__ __launch_bounds__(256) void k4_conv2(const float* __restrict__ h2,
                                                const float* __restrict__ w,
                                                const float* __restrict__ bias,
                                                const float* __restrict__ bn1,
                                                float* __restrict__ h3,
                                                float* __restrict__ part2) {
  __shared__ __align__(16) float ins[4 * 96 * 26];
  __shared__ __align__(16) float wls[16 * 241];
  __shared__ float A1s[96], B1s[96];
  __shared__ float red[16 * 16 * 2];
  const int tid = threadIdx.x;
  const int wg = blockIdx.x;

  if (tid < 96) {
    A1s[tid] = bn1[tid * 2 + 0];
    B1s[tid] = bn1[tid * 2 + 1];
  }
  __syncthreads();
  for (int i = tid; i < 9600; i += 256) {
    int img = i / 2400;
    int e = i - img * 2400;
    int ci = e / 25;
    int t = e - ci * 25;
    float v = h2[(size_t)(wg * 4 + img) * 2400 + e];
    v = A1s[ci] * v + B1s[ci];
    v = (v >= 0.f) ? v : 0.01f * v;
    ins[img * 2496 + ci * 26 + t] = v;
  }
  for (int i = tid; i < 4 * 96; i += 256) ins[(i / 96) * 2496 + (i % 96) * 26 + 25] = 0.f;

  const int img = tid >> 6;
  const int co = (tid >> 2) & 15;
  const int tg = tid & 3;
  const int t0s[4] = {0, 6, 11, 16};
  const int t0 = t0s[tg];
  const int tl = (tg == 0) ? 6 : 5;
  float acc[6] = {0.f, 0.f, 0.f, 0.f, 0.f, 0.f};

  for (int cc = 0; cc < 2; ++cc) {
    __syncthreads();
    for (int i = tid; i < 3840; i += 256) {
      int cw = i / 240;
      int r = i - cw * 240;
      wls[cw * 241 + r] = w[cw * 480 + cc * 240 + r];
    }
    __syncthreads();
    for (int ci = 0; ci < 48; ++ci) {
      float xv[10];
#pragma unroll
      for (int j = 0; j < 10; ++j) xv[j] = ins[img * 2496 + (cc * 48 + ci) * 26 + t0 + j];
      float wv[5];
#pragma unroll
      for (int d = 0; d < 5; ++d) wv[d] = wls[co * 241 + ci * 5 + d];
#pragma unroll
      for (int t = 0; t < 6; ++t) {
        float s = acc[t];
#pragma unroll
        for (int d = 0; d < 5; ++d) s += xv[t + d] * wv[d];
        acc[t] = s;
      }
    }
  }
  const float bval = bias[co];
  float s1 = 0.f, s2 = 0.f;
  const int n = wg * 4 + img;
  for (int t = 0; t < 6; ++t) {
    if (t < tl) {
      float v = acc[t] + bval;
      h3[(size_t)n * 336 + co * 21 + t0 + t] = v;
      s1 += v;
      s2 += v * v;
    }
  }
  red[(co * 16 + img * 4 + tg) * 2 + 0] = s1;
  red[(co * 16 + img * 4 + tg) * 2 + 1] = s2;
  __syncthreads();
  if (tid < 16) {
    float s = 0.f, q = 0.f;
    for (int k = 0; k < 16; ++k) {
      s += red[(tid * 16 + k) * 2 + 0];
      q += red[(tid * 16 + k) * 2 + 1];
    }
    part2[((size_t)wg * 16 + tid) * 2 + 0] = s;
    part2[((size_t)wg * 16 + tid) * 2 + 1] = q;
  }
}

// ------------------------------ K6: OAS + Cholesky ---------------------------
__global__ __launch_bounds__(256) void k6_oas(const float* __restrict__ h3,
                                              const float* __restrict__ bn2,
                                              float* __restrict__ xd,
                                              float* __restrict__ xo) {
  __shared__ float X[4][21 * 17 + 3];
  __shared__ float A[4][16 * 17];
  __shared__ float mcol[4][16];
  const int tid = threadIdx.x;
  const int wid = tid >> 6;
  const int lane = tid & 63;
  const int n = blockIdx.x * 4 + wid;
  const float* hp = h3 + (size_t)n * 336;

  for (int e = lane; e < 336; e += 64) {
    int c = e / 21;
    int t = e - c * 21;
    float v = hp[e];
    v = bn2[c * 2 + 0] * v + bn2[c * 2 + 1];
    v = (v >= 0.f) ? v : 0.01f * v;
    X[wid][t * 17 + c] = v;
  }
  __syncthreads();
  if (lane < 16) {
    float s = 0.f;
    for (int t = 0; t < 21; ++t) s += X[wid][t * 17 + lane];
    mcol[wid][lane] = s * (1.f / 21.f);
  }
  __syncthreads();
  for (int e = lane; e < 336; e += 64) {
    int t = e / 16;
    int c = e - t * 16;
    X[wid][t * 17 + c] -= mcol[wid][c];
  }
  __syncthreads();

  float tr_p = 0.f, al_p = 0.f;
  float ent[3];
  int ei[3], ej[3], ne = 0;
  for (int e = lane; e < 136; e += 64) {
    int i = 0, e2 = e;
    while (e2 >= 16 - i) { e2 -= 16 - i; i++; }
    int j = i + e2;
    float s = 0.f;
    for (int t = 0; t < 21; ++t) s += X[wid][t * 17 + i] * X[wid][t * 17 + j];
    s *= (1.f / 20.f);
    ent[ne] = s; ei[ne] = i; ej[ne] = j; ne++;
    if (i == j) tr_p += s;
    al_p += s * s * ((i == j) ? 1.f : 2.f);
  }
  for (int m = 1; m < 64; m <<= 1) {
    tr_p += __shfl_xor(tr_p, m);
    al_p += __shfl_xor(al_p, m);
  }
  const float mu = tr_p * (1.f / 16.f);
  const float alpha = al_p * (1.f / 256.f);
  const float num = alpha + mu * mu;
  const float den = 22.f * (alpha - mu * mu * (1.f / 16.f));
  const float shr = (den == 0.f) ? 1.f : fminf(num / den, 1.f);
  for (int q = 0; q < ne; ++q) {
    float c = (1.f - shr) * ent[q] + ((ei[q] == ej[q]) ? shr * mu : 0.f);
    A[wid][ei[q] * 17 + ej[q]] = c;
    A[wid][ej[q] * 17 + ei[q]] = c;
  }
  __syncthreads();

  for (int k = 0; k < 16; ++k) {
    float akk = A[wid][k * 17 + k];
    __syncthreads();
    float d = sqrtf(akk);
    float rd = 1.f / d;
    if (lane == k) A[wid][k * 17 + k] = d;
    if (lane > k && lane < 16) A[wid][lane * 17 + k] *= rd;
    __syncthreads();
    if (lane > k && lane < 16) {
      float Lik = A[wid][lane * 17 + k];
      for (int j = k + 1; j <= lane; ++j) A[wid][lane * 17 + j] -= Lik * A[wid][j * 17 + k];
    }
    __syncthreads();
  }
  if (lane < 16) xd[(size_t)n * 16 + lane] = A[wid][lane * 17 + lane];
  for (int p = lane; p < 120; p += 64) {
    int i = 1, p2 = p;
    while (p2 >= i) { p2 -= i; i++; }
    xo[(size_t)n * 120 + p] = A[wid][i * 17 + p2];
  }
}

// ------------------------------ K0: pack B-fragments ------------------------
// u32 slot within region: tile=(t*NT+nt), rem: lane=rem/4, word=rem%4.
// elements k = t*32 + 8*(lane>>4) + 2*word (+1), col = nt*16 + (lane&15).
__global__ __launch_bounds__(256) void k0_pack(const float* __restrict__ w0,
                                               const float* __restrict__ w1,
                                               const float* __restrict__ w2,
                                               const float* __restrict__ w3,
                                               const float* __restrict__ wxo,
                                               const float* __restrict__ who,
                                               uint32_t* __restrict__ dst) {
  int i = blockIdx.x * 256 + threadIdx.x;
  if (i >= PK2_TOT) return;
  int j = i, kind, NT;
  if (j < OFF_W1)       { kind = 0; NT = 16; }
  else if (j < OFF_W2)  { kind = 1; NT = 16; j -= OFF_W1; }
  else if (j < OFF_W3)  { kind = 2; NT = 16; j -= OFF_W2; }
  else if (j < OFF_GRZ) { kind = 3; NT = 9;  j -= OFF_W3; }
  else if (j < OFF_GNX) { kind = 4; NT = 15; j -= OFF_GRZ; }
  else if (j < OFF_GNH) { kind = 5; NT = 8;  j -= OFF_GNX; }
  else                  { kind = 6; NT = 8;  j -= OFF_GNH; }
  const int tile = j >> 8;
  const int rem = j & 255;
  const int l = rem >> 2;
  const int wd = rem & 3;
  const int t = tile / NT;
  const int nt = tile - t * NT;
  const int col = nt * 16 + (l & 15);
  const int kk = t * 32 + 8 * (l >> 4) + 2 * wd;

  float v[2];
#pragma unroll
  for (int q = 0; q < 2; ++q) {
    const int k = kk + q;
    float s = 0.f;
    if (kind == 0)      { if (k < 136) s = w0[k * 256 + col]; }
    else if (kind == 1) { s = w1[k * 256 + col]; }
    else if (kind == 2) { s = w2[k * 256 + col]; }
    else if (kind == 3) { if (col < 136) s = w3[k * 136 + col]; }
    else if (kind == 4) {
      if (k < 120) s = wxo[k * 360 + col];
      else if (k >= 128 && k < 248) s = who[(k - 128) * 360 + col];
    } else if (kind == 5) { if (k < 120 && col < 120) s = wxo[k * 360 + 240 + col]; }
    else                  { if (k < 120 && col < 120) s = who[k * 360 + 240 + col]; }
    v[q] = s;
  }
  union { f16 h[2]; uint32_t u; } cv;
  cv.h[0] = (f16)v[0];
  cv.h[1] = (f16)v[1];
  dst[i] = cv.u;
}

// ------------------------------ K7 helpers ----------------------------------
// X buffers: 16 rows x 256 f16, row stride 512B, XOR swizzle on byte bits 4-6.
__device__ __forceinline__ uint4 aread(const f16* X, int t, int m, int g) {
  const int byte = m * 512 + (((t * 64 + 16 * g)) ^ ((m & 7) << 4));
  return *(const uint4*)((const char*)X + byte);
}
__device__ __forceinline__ void xwrite(f16* X, int row, int col, float v) {
  const int byte = row * 512 + ((col * 2) ^ ((row & 7) << 4));
  *(f16*)((char*)X + byte) = (f16)v;
}

union UF { uint4 u; f16x8 h; };

// MLP layer: D = Xin @ W; tanh(D+b) -> Xout, or hcf += 0.25*(D+b) (L4).
template <int KT, int NT, bool TOHCF>
__device__ __forceinline__ void mlp_layer(const f16* Xin, const uint4* B,
                                          const float* bias, f16* Xout,
                                          float* hcf, int w, int l) {
  const int m = l & 15;
  const int g = l >> 4;
  uint4 af[KT];
#pragma unroll
  for (int t = 0; t < KT; ++t) af[t] = aread(Xin, t, m, g);
  for (int nt = w; nt < NT; nt += 8) {
    uint4 bf[KT];
#pragma unroll
    for (int t = 0; t < KT; ++t) bf[t] = B[(t * NT + nt) * 64 + l];
    f32x4 acc = {0.f, 0.f, 0.f, 0.f};
#pragma unroll
    for (int t = 0; t < KT; ++t) {
      UF a; a.u = af[t];
      UF b; b.u = bf[t];
      acc = __builtin_amdgcn_mfma_f32_16x16x32_f16(a.h, b.h, acc, 0, 0, 0);
    }
    const int col = nt * 16 + m;
    if (!TOHCF) {
      const float bb = bias[col];
#pragma unroll
      for (int i2 = 0; i2 < 4; ++i2)
        xwrite(Xout, 4 * g + i2, col, tanhf(acc[i2] + bb));
    } else {
      if (col < 136) {
        const float bb = bias[col];
#pragma unroll
        for (int i2 = 0; i2 < 4; ++i2)
          hcf[(4 * g + i2) * 160 + col] += 0.25f * (acc[i2] + bb);
      }
    }
  }
}

// Gate matmul: GO[row][gooff+col] = (Xin[:, ktoff-tiles] @ B)
template <int KT, int NT, int KTOFF, int GOOFF>
__device__ __forceinline__ void gate_mm(const f16* Xin, const uint4* B,
                                        float* GO, int w, int l) {
  const int m = l & 15;
  const int g = l >> 4;
  uint4 af[KT];
#pragma unroll
  for (int t = 0; t < KT; ++t) af[t] = aread(Xin, t + KTOFF, m, g);
  for (int nt = w; nt < NT; nt += 8) {
    uint4 bf[KT];
#pragma unroll
    for (int t = 0; t < KT; ++t) bf[t] = B[(t * NT + nt) * 64 + l];
    f32x4 acc = {0.f, 0.f, 0.f, 0.f};
#pragma unroll
    for (int t = 0; t < KT; ++t) {
      UF a; a.u = af[t];
      UF b; b.u = bf[t];
      acc = __builtin_amdgcn_mfma_f32_16x16x32_f16(a.h, b.h, acc, 0, 0, 0);
    }
    const int col = nt * 16 + m;
#pragma unroll
    for (int i2 = 0; i2 < 4; ++i2)
      GO[(4 * g + i2) * 512 + GOOFF + col] = acc[i2];
  }
}

// ------------------------------ K7: scan (MFMA, 16 rows/block) --------------
__global__ __launch_bounds__(512, 1) void k7_scan(
    const float* __restrict__ xdv, const float* __restrict__ xov,
    const float* __restrict__ wxd, const float* __restrict__ whd,
    const float* __restrict__ bdv, const float* __restrict__ bov,
    const uint32_t* __restrict__ pk,
    const float* __restrict__ b0, const float* __restrict__ b1,
    const float* __restrict__ b2, const float* __restrict__ b3,
    const float* __restrict__ cw, const float* __restrict__ cbv,
    float* __restrict__ out) {
  __shared__ __align__(16) f16 XA[16 * 256];
  __shared__ __align__(16) f16 XB[16 * 256];
  __shared__ __align__(16) f16 XC[16 * 256];
  __shared__ __align__(16) f16 XG[16 * 256];
  __shared__ __align__(16) float GO[16 * 512];
  __shared__ __align__(16) float hcf[16 * 160];
  __shared__ __align__(16) float xdlv[16 * 16];
  __shared__ __align__(16) float ehl[16 * 16];
  __shared__ __align__(16) float G2[16 * 96];
  __shared__ __align__(16) float wdaT[48 * 16], whaT[48 * 16];
  __shared__ float b0l[256], b1l[256], b2l[256], b3l[144], bovl[360], bdvl[48];

  const int tid = threadIdx.x;
  const int w = tid >> 6;
  const int l = tid & 63;
  const int blk = blockIdx.x;

  const uint4* BW0 = (const uint4*)(pk + OFF_W0);
  const uint4* BW1 = (const uint4*)(pk + OFF_W1);
  const uint4* BW2 = (const uint4*)(pk + OFF_W2);
  const uint4* BW3 = (const uint4*)(pk + OFF_W3);
  const uint4* BRZ = (const uint4*)(pk + OFF_GRZ);
  const uint4* BNX = (const uint4*)(pk + OFF_GNX);
  const uint4* BNH = (const uint4*)(pk + OFF_GNH);

  // init LDS constants
  for (int i = tid; i < 768; i += 512) {
    int k = i / 48, c = i - k * 48;
    wdaT[c * 16 + k] = fabsf(wxd[i]);
    whaT[c * 16 + k] = fabsf(whd[i]);
  }
  for (int i = tid; i < 256; i += 512) { b0l[i] = b0[i]; b1l[i] = b1[i]; b2l[i] = b2[i]; }
  for (int i = tid; i < 144; i += 512) b3l[i] = (i < 136) ? b3[i] : 0.f;
  for (int i = tid; i < 360; i += 512) bovl[i] = bov[i];
  if (tid < 48) bdvl[tid] = fabsf(bdv[tid]);
  for (int i = tid; i < 16 * 160; i += 512) hcf[i] = 0.f;
  __syncthreads();

#pragma unroll 1
  for (int s = 0; s < 50; ++s) {
    // ---- ODE: 4 Euler steps ----
#pragma unroll 1
    for (int e = 0; e < 4; ++e) {
      // build XA (16 x 160 f16) from hcf
      for (int i = tid; i < 16 * 160; i += 512) {
        int row = i / 160, c = i - row * 160;
        xwrite(XA, row, c, (c < 136) ? hcf[row * 160 + c] : 0.f);
      }
      __syncthreads();
      mlp_layer<5, 16, false>(XA, BW0, b0l, XB, hcf, w, l);
      __syncthreads();
      mlp_layer<8, 16, false>(XB, BW1, b1l, XC, hcf, w, l);
      __syncthreads();
      mlp_layer<8, 16, false>(XC, BW2, b2l, XB, hcf, w, l);
      __syncthreads();
      mlp_layer<8, 9, true>(XB, BW3, b3l, (f16*)nullptr, hcf, w, l);
      __syncthreads();
    }

    // ---- build gate inputs ----
    for (int i = tid; i < 16 * 256; i += 512) {
      int row = i >> 8, c = i & 255;
      float v = 0.f;
      if (c < 120) v = xov[((size_t)(blk * 16 + row) * 50 + s) * 120 + c];
      else if (c >= 128 && c < 248) v = hcf[row * 160 + 16 + (c - 128)];
      xwrite(XG, row, c, v);
    }
    for (int i = tid; i < 256; i += 512) {
      int row = i >> 4, k = i & 15;
      xdlv[i] = xdv[((size_t)(blk * 16 + row) * 50 + s) * 16 + k];
      ehl[i] = expf(hcf[row * 160 + k]);
    }
    __syncthreads();

    // ---- gate matmuls (MFMA) + d-gate dots (VALU) ----
    gate_mm<8, 15, 0, 0>(XG, BRZ, GO, w, l);
    gate_mm<4, 8, 0, 256>(XG, BNX, GO, w, l);
    gate_mm<4, 8, 4, 384>(XG, BNH, GO, w, l);
    for (int i = tid; i < 1536; i += 512) {
      int row = i / 96, c = i - row * 96;
      const float4* sv = (const float4*)((c < 48) ? &xdlv[row * 16] : &ehl[row * 16]);
      const float4* wv = (const float4*)((c < 48) ? &wdaT[c * 16] : &whaT[(c - 48) * 16]);
      float a = 0.f;
#pragma unroll
      for (int q = 0; q < 4; ++q) {
        float4 xq = sv[q], wq = wv[q];
        a += xq.x * wq.x + xq.y * wq.y + xq.z * wq.z + xq.w * wq.w;
      }
      G2[row * 96 + c] = a;
    }
    __syncthreads();

    // ---- state updates ----
    for (int i = tid; i < 1920; i += 512) {
      int row = i / 120, e2 = i - row * 120;
      float r = sigm(GO[row * 512 + e2] + bovl[e2]);
      float z = sigm(GO[row * 512 + 120 + e2] + bovl[120 + e2]);
      float ng = tanhf(GO[row * 512 + 256 + e2] + r * GO[row * 512 + 384 + e2] + bovl[240 + e2]);
      float ho = hcf[row * 160 + 16 + e2];
      hcf[row * 160 + 16 + e2] = ng + z * (ho - ng);
    }
    if (tid < 256) {
      int row = tid >> 4, t = tid & 15;
      float ixr = G2[row * 96 + t], ixi = G2[row * 96 + 16 + t], ixn = G2[row * 96 + 32 + t];
      float hhr = G2[row * 96 + 48 + t], hhi = G2[row * 96 + 64 + t], hhn = G2[row * 96 + 80 + t];
      float br = bdvl[t], bi = bdvl[16 + t], bn = bdvl[32 + t];
      float r = sigm(br * ixr * hhr);
      float z = sigm(bi * ixi * hhi);
      float sp = bn * ixn * r * hhn;
      float ng = (sp > 20.f) ? sp : log1pf(expf(sp));
      float ldp = hcf[row * 160 + t];
      hcf[row * 160 + t] = z * ldp + (1.f - z) * logf(ng);
    }
    __syncthreads();
  }

  // ---- classifier ----
  if (tid < 80) {
    int row = tid / 5, c = tid - row * 5;
    float a = cbv[c];
    for (int k = 0; k < 136; ++k) a += hcf[row * 160 + k] * cw[k * 5 + c];
    out[(size_t)(blk * 16 + row) * 5 + c] = a;
  }
}

// ------------------------------ launch ------------------------------
extern "C" void kernel_launch(void* const* d_in, const int* in_sizes, int n_in,
                              void* d_out, int out_size, void* d_ws, size_t ws_size,
                              hipStream_t stream) {
  const float* x       = (const float*)d_in[0];
  const float* fw      = (const float*)d_in[1];
  const float* s_tri   = (const float*)d_in[2];
  const float* conv1_w = (const float*)d_in[3];
  const float* conv1_b = (const float*)d_in[4];
  const float* bn1_g   = (const float*)d_in[5];
  const float* bn1_b   = (const float*)d_in[6];
  const float* conv2_w = (const float*)d_in[7];
  const float* conv2_b = (const float*)d_in[8];
  const float* bn2_g   = (const float*)d_in[9];
  const float* bn2_b   = (const float*)d_in[10];
  const float* wx_d    = (const float*)d_in[11];
  const float* wh_d    = (const float*)d_in[12];
  const float* bias_d  = (const float*)d_in[13];
  const float* wx_o    = (const float*)d_in[14];
  const float* wh_o    = (const float*)d_in[15];
  const float* bias_o  = (const float*)d_in[16];
  const float* ode_w0  = (const float*)d_in[17];
  const float* ode_b0  = (const float*)d_in[18];
  const float* ode_w1  = (const float*)d_in[19];
  const float* ode_b1  = (const float*)d_in[20];
  const float* ode_w2  = (const float*)d_in[21];
  const float* ode_b2  = (const float*)d_in[22];
  const float* ode_w3  = (const float*)d_in[23];
  const float* ode_b3  = (const float*)d_in[24];
  const float* cls_w   = (const float*)d_in[25];
  const float* cls_b   = (const float*)d_in[26];

  float* ws = (float*)d_ws;
  float* h1  = ws;                    // 8,908,800 floats (K1->K2), then dead
  float* h3  = ws;                    // 1,075,200 floats (K4->K6)
  float* xd  = ws + 1075200;          // 51,200
  float* xo  = ws + 1126400;          // 384,000
  float* h2  = ws + 8908800;          // 7,680,000 (K2->K4), then reused by K0
  float* p1  = ws + 16588800;         // 614,400
  float* bn1 = ws + 17203200;         // 192
  float* p2  = ws + 17203392;         // 25,600
  float* bn2 = ws + 17228992;         // 32
  uint32_t* pk = (uint32_t*)(ws + 8908800);  // packed B-fragments (dead h2)

  hipLaunchKernelGGL(k1_fb,   dim3(NIMG),   dim3(256), 0, stream, x, fw, s_tri, h1);
  hipLaunchKernelGGL(k2_conv1,dim3(NIMG/2), dim3(256), 0, stream, h1, conv1_w, conv1_b, h2, p1);
  hipLaunchKernelGGL(k3_bn1,  dim3(96),     dim3(256), 0, stream, p1, bn1_g, bn1_b, bn1);
  hipLaunchKernelGGL(k4_conv2,dim3(NIMG/4), dim3(256), 0, stream, h2, conv2_w, conv2_b, bn1, h3, p2);
  hipLaunchKernelGGL(k5_bn2,  dim3(16),     dim3(256), 0, stream, p2, bn2_g, bn2_b, bn2);
  hipLaunchKernelGGL(k6_oas,  dim3(NIMG/4), dim3(256), 0, stream, h3, bn2, xd, xo);
  hipLaunchKernelGGL(k0_pack, dim3((PK2_TOT + 255) / 256), dim3(256), 0, stream,
                     ode_w0, ode_w1, ode_w2, ode_w3, wx_o, wh_o, pk);
  hipLaunchKernelGGL(k7_scan, dim3(4),      dim3(512), 0, stream,
                     xd, xo, wx_d, wh_d, bias_d, bias_o, pk,
                     ode_b0, ode_b1, ode_b2, ode_b3, cls_w, cls_b, (float*)d_out);
}